// Round 4
// baseline (173.229 us; speedup 1.0000x reference)
//
#include <hip/hip_runtime.h>
#include <hip/hip_bf16.h>

#define D_ 256
#define HW_ 1024

typedef short short8 __attribute__((ext_vector_type(8)));
typedef float float4v __attribute__((ext_vector_type(4)));
typedef int int4v __attribute__((ext_vector_type(4)));

__device__ __forceinline__ unsigned short f2bf(float f) {
  unsigned u = __builtin_bit_cast(unsigned, f);
  return (unsigned short)((u + 0x7fffu + ((u >> 16) & 1u)) >> 16);
}

__device__ __forceinline__ void async16(void* lds, const void* g) {
  __builtin_amdgcn_global_load_lds(
      (__attribute__((address_space(1))) const unsigned int*)g,
      (__attribute__((address_space(3))) unsigned int*)lds, 16, 0, 0);
}

// ---- prep: cnorm + bf16(-2c) swizzled image, 32-code chunks (16KB each) ----
// chunk=k>>5, row=k&31 (512B rows); byte for feature d at (2d)^((row&15)<<5)
__global__ __launch_bounds__(256) void vq_prep(const float* __restrict__ cb,
                                               unsigned short* __restrict__ cbimg,
                                               float* __restrict__ cnorm) {
  int k = blockIdx.x;   // 0..1023
  int t = threadIdx.x;  // 0..255 (= feature d)
  float c = cb[k * D_ + t];
  float s = c * c;
#pragma unroll
  for (int off = 1; off < 64; off <<= 1) s += __shfl_xor(s, off, 64);
  __shared__ float wsum[4];
  if ((t & 63) == 0) wsum[t >> 6] = s;
  __syncthreads();
  if (t == 0) cnorm[k] = wsum[0] + wsum[1] + wsum[2] + wsum[3];
  int row = k & 31, chunk = k >> 5;
  int byteoff = (2 * t) ^ ((row & 15) << 5);
  *(unsigned short*)((char*)cbimg + chunk * 16384 + row * 512 + byteoff) =
      f2bf(-2.0f * c);
}

// ---- main: stage pts + stream codebook + argmin + loss + gather-out ----
// 256 blocks x 256 thr (4 waves). Wave w owns 64 points (tile w).
// Each wave covers all 32 codes of each chunk (af=2), 32 chunks.
__global__ __launch_bounds__(256, 4) void vq_main(const float* __restrict__ lat,
                                                  const short8* __restrict__ cbimg,
                                                  const float* __restrict__ cnorm,
                                                  const float* __restrict__ cb,
                                                  float* __restrict__ out,
                                                  float* __restrict__ part) {
  __shared__ short8 dbuf[2][1024];   // 32KB: point tiles, then cb dbuf
  __shared__ float cnorm_s[1024];    // 4KB
  __shared__ int idx_s[256];         // 1KB

  const int tid = threadIdx.x;
  const int w = tid >> 6, lane = tid & 63;
  const int q = lane >> 4, c = lane & 15;
  const int blk = blockIdx.x;
  const int b = blk >> 2;             // batch index
  const int hwb = (blk & 3) << 8;     // hw base (256 pts/block)

  cnorm_s[tid] = cnorm[tid];
  cnorm_s[tid + 256] = cnorm[tid + 256];
  cnorm_s[tid + 512] = cnorm[tid + 512];
  cnorm_s[tid + 768] = cnorm[tid + 768];

  // ---- stage 4 tiles of 64 pts; wave t extracts tile t into registers ----
  unsigned short* tileu = (unsigned short*)&dbuf[0][0];  // 64 rows x 512B
  short8 bfrag[4][8];
  float fn[4];
  const int jb = (tid >> 6) * 8;      // this thread's 8 d-groups (of 32)
#pragma unroll 1
  for (int t = 0; t < 4; ++t) {
#pragma unroll
    for (int jj = 0; jj < 8; ++jj) {
      int j = jb + jj;                // features 8j..8j+7
      short8 v;
#pragma unroll
      for (int e = 0; e < 8; ++e) {
        float f = lat[((size_t)(b * D_ + j * 8 + e)) * HW_ + hwb + t * 64 + lane];
        v[e] = (short)f2bf(f);
      }
      // b128 write, bank-spread via ((hw&15)<<4) ushort-XOR (2-way max)
      *(short8*)&tileu[lane * 256 + ((j * 8) ^ ((lane & 15) << 4))] = v;
    }
    __syncthreads();
    if (w == t) {
#pragma unroll
      for (int pf = 0; pf < 4; ++pf) {
        int hw = pf * 16 + c;
#pragma unroll
        for (int kk = 0; kk < 8; ++kk) {
          int s = (kk << 2) | q;
          bfrag[pf][kk] =
              *(const short8*)&tileu[hw * 256 + ((s * 8) ^ ((hw & 15) << 4))];
        }
        float a = 0.f;
#pragma unroll
        for (int kk = 0; kk < 8; ++kk)
#pragma unroll
          for (int e = 0; e < 8; ++e) {
            unsigned u = ((unsigned)(unsigned short)bfrag[pf][kk][e]) << 16;
            float f = __builtin_bit_cast(float, u);
            a += f * f;
          }
        fn[pf] = a;
      }
#pragma unroll
      for (int pf = 0; pf < 4; ++pf) {
        fn[pf] += __shfl_xor(fn[pf], 16, 64);
        fn[pf] += __shfl_xor(fn[pf], 32, 64);
      }
    }
    __syncthreads();
  }

  // ---- stream 32 codebook chunks (16KB, double-buffered) ----
  float runD[4];
  int runI[4];
#pragma unroll
  for (int pf = 0; pf < 4; ++pf) { runD[pf] = 3.0e38f; runI[pf] = 0x7fffffff; }

#pragma unroll
  for (int r = 0; r < 4; ++r)
    async16(&dbuf[0][r * 256 + tid], cbimg + (r * 256 + tid));
  __syncthreads();

  int buf = 0;
#pragma unroll 1
  for (int chunk = 0; chunk < 32; ++chunk) {
    if (chunk < 31) {
#pragma unroll
      for (int r = 0; r < 4; ++r)
        async16(&dbuf[buf ^ 1][r * 256 + tid],
                cbimg + ((chunk + 1) * 1024 + r * 256 + tid));
    }
    float4v acc[2][4];
#pragma unroll
    for (int af = 0; af < 2; ++af) {
      float4v cn = *(const float4v*)&cnorm_s[chunk * 32 + af * 16 + q * 4];
#pragma unroll
      for (int pf = 0; pf < 4; ++pf) acc[af][pf] = cn;
    }
#pragma unroll
    for (int kk = 0; kk < 8; ++kk) {
      short8 a[2];
#pragma unroll
      for (int af = 0; af < 2; ++af)
        a[af] = dbuf[buf][(af * 16 + c) * 32 + (((kk << 2) | q) ^ (c << 1))];
#pragma unroll
      for (int af = 0; af < 2; ++af)
#pragma unroll
        for (int pf = 0; pf < 4; ++pf)
          acc[af][pf] = __builtin_amdgcn_mfma_f32_16x16x32_bf16(
              a[af], bfrag[pf][kk], acc[af][pf], 0, 0, 0);
    }
    // lane-local scan (ascending code index; strict < = first occurrence)
#pragma unroll
    for (int pf = 0; pf < 4; ++pf)
#pragma unroll
      for (int af = 0; af < 2; ++af) {
        int cb0 = chunk * 32 + af * 16 + q * 4;
#pragma unroll
        for (int r = 0; r < 4; ++r) {
          float dv = acc[af][pf][r];
          if (dv < runD[pf]) { runD[pf] = dv; runI[pf] = cb0 + r; }
        }
      }
    __syncthreads();
    buf ^= 1;
  }

  // ---- deferred butterfly merge; write idx to LDS; loss partial ----
#pragma unroll
  for (int pf = 0; pf < 4; ++pf) {
#pragma unroll
    for (int di = 16; di < 64; di <<= 1) {
      float od = __shfl_xor(runD[pf], di, 64);
      int oi = __shfl_xor(runI[pf], di, 64);
      if (od < runD[pf] || (od == runD[pf] && oi < runI[pf])) {
        runD[pf] = od; runI[pf] = oi;
      }
    }
  }
  float selD = q == 0 ? runD[0] : q == 1 ? runD[1] : q == 2 ? runD[2] : runD[3];
  int selI = q == 0 ? runI[0] : q == 1 ? runI[1] : q == 2 ? runI[2] : runI[3];
  float selF = q == 0 ? fn[0] : q == 1 ? fn[1] : q == 2 ? fn[2] : fn[3];
  idx_s[w * 64 + q * 16 + c] = selI;
  float lv = selD + selF;  // ||f - c_best||^2 for this lane's point
#pragma unroll
  for (int off = 1; off < 64; off <<= 1) lv += __shfl_xor(lv, off, 64);
  if (lane == 0) part[blk * 4 + w] = lv;
  __syncthreads();

  // ---- gather-out: out[b,d,hw] = cb[idx[hw]][d] (fp32, L2-resident rows) ----
  const int quad = tid & 63, dg = tid >> 6;
  int4v idx4 = *(const int4v*)&idx_s[quad * 4];
  const size_t outbase = ((size_t)b * D_) * HW_ + hwb + quad * 4;
#pragma unroll 1
  for (int it = 0; it < 64; ++it) {
    int d = it * 4 + dg;
    float4v v;
#pragma unroll
    for (int i = 0; i < 4; ++i) v[i] = cb[(size_t)idx4[i] * D_ + d];
    *(float4v*)&out[outbase + (size_t)d * HW_] = v;
  }
}

// ---- finalize: loss = 1.25 * mean ----
__global__ __launch_bounds__(256) void vq_fin(const float* __restrict__ part,
                                              float* __restrict__ outs) {
  int t = threadIdx.x;
  float s = part[t] + part[t + 256] + part[t + 512] + part[t + 768];
#pragma unroll
  for (int off = 1; off < 64; off <<= 1) s += __shfl_xor(s, off, 64);
  __shared__ float w4[4];
  if ((t & 63) == 0) w4[t >> 6] = s;
  __syncthreads();
  if (t == 0) *outs = (w4[0] + w4[1] + w4[2] + w4[3]) * (1.25f / 16777216.0f);
}

extern "C" void kernel_launch(void* const* d_in, const int* in_sizes, int n_in,
                              void* d_out, int out_size, void* d_ws, size_t ws_size,
                              hipStream_t stream) {
  const float* lat = (const float*)d_in[0];
  const float* cb = (const float*)d_in[1];
  float* out = (float*)d_out;
  char* ws = (char*)d_ws;
  unsigned short* cbimg = (unsigned short*)ws;   // 512 KB (bf16 -2c image)
  float* cnorm = (float*)(ws + 524288);          // 4 KB
  float* partial = (float*)(ws + 528384);        // 4 KB (1024 floats)

  vq_prep<<<1024, 256, 0, stream>>>(cb, cbimg, cnorm);
  vq_main<<<256, 256, 0, stream>>>(lat, (const short8*)cbimg, cnorm, cb, out,
                                   partial);
  vq_fin<<<1, 256, 0, stream>>>(partial, out + 16777216);
}

// Round 5
// 90.370 us; speedup vs baseline: 1.9169x; 1.9169x over previous
//
#include <hip/hip_runtime.h>
#include <hip/hip_bf16.h>

#define D_ 256
#define HW_ 1024

typedef short short8 __attribute__((ext_vector_type(8)));
typedef float float4v __attribute__((ext_vector_type(4)));
typedef int int4v __attribute__((ext_vector_type(4)));

__device__ __forceinline__ unsigned short f2bf(float f) {
  unsigned u = __builtin_bit_cast(unsigned, f);
  return (unsigned short)((u + 0x7fffu + ((u >> 16) & 1u)) >> 16);
}

__device__ __forceinline__ void async16(void* lds, const void* g) {
  __builtin_amdgcn_global_load_lds(
      (__attribute__((address_space(1))) const unsigned int*)g,
      (__attribute__((address_space(3))) unsigned int*)lds, 16, 0, 0);
}

// ---- prep: cnorm + bf16(-2c) swizzled image, 32-code chunks (16KB each) ----
// chunk=k>>5, row=k&31 (512B rows); byte for feature d at (2d)^((row&15)<<5)
__global__ __launch_bounds__(256) void vq_prep(const float* __restrict__ cb,
                                               unsigned short* __restrict__ cbimg,
                                               float* __restrict__ cnorm) {
  int k = blockIdx.x;   // 0..1023
  int t = threadIdx.x;  // 0..255 (= feature d)
  float c = cb[k * D_ + t];
  float s = c * c;
#pragma unroll
  for (int off = 1; off < 64; off <<= 1) s += __shfl_xor(s, off, 64);
  __shared__ float wsum[4];
  if ((t & 63) == 0) wsum[t >> 6] = s;
  __syncthreads();
  if (t == 0) cnorm[k] = wsum[0] + wsum[1] + wsum[2] + wsum[3];
  int row = k & 31, chunk = k >> 5;
  int byteoff = (2 * t) ^ ((row & 15) << 5);
  *(unsigned short*)((char*)cbimg + chunk * 16384 + row * 512 + byteoff) =
      f2bf(-2.0f * c);
}

// ---- main: stage pts + stream codebook + argmin + loss + gather-out ----
// 512 blocks x 256 thr (4 waves). Wave w owns 32 points (pf=2).
// NO forced min-occupancy (R4 lesson: bounds below footprint => spill disaster).
__global__ __launch_bounds__(256) void vq_main(const float* __restrict__ lat,
                                               const short8* __restrict__ cbimg,
                                               const float* __restrict__ cnorm,
                                               const float* __restrict__ cb,
                                               float* __restrict__ out,
                                               float* __restrict__ part) {
  __shared__ short8 dbuf[2][1024];   // 32KB: point tiles first, then cb dbuf
  __shared__ float cnorm_s[1024];    // 4KB
  __shared__ int idx_s[128];         // 0.5KB

  const int tid = threadIdx.x;
  const int w = tid >> 6, lane = tid & 63;
  const int q = lane >> 4, c = lane & 15;
  const int blk = blockIdx.x;
  const int b = blk >> 3;             // batch index
  const int hwb = (blk & 7) << 7;     // hw base (128 pts/block)

  cnorm_s[tid] = cnorm[tid];
  cnorm_s[tid + 256] = cnorm[tid + 256];
  cnorm_s[tid + 512] = cnorm[tid + 512];
  cnorm_s[tid + 768] = cnorm[tid + 768];

  // ---- stage 2 tiles of 64 pts; waves 2t,2t+1 extract tile t ----
  // (R4's proven conflict-free pattern: coalesced dword loads, b128 LDS writes)
  unsigned short* tileu = (unsigned short*)&dbuf[0][0];  // 64 rows x 512B
  short8 bfrag[2][8];
  float fn[2];
  const int jb = w * 8;               // this thread's 8 feature-octets
#pragma unroll 1
  for (int t = 0; t < 2; ++t) {
#pragma unroll 4
    for (int jj = 0; jj < 8; ++jj) {
      int j = jb + jj;                // features 8j..8j+7
      short8 v;
#pragma unroll
      for (int e = 0; e < 8; ++e) {
        float f = lat[((size_t)(b * D_ + j * 8 + e)) * HW_ + hwb + t * 64 + lane];
        v[e] = (short)f2bf(f);
      }
      *(short8*)&tileu[lane * 256 + ((j * 8) ^ ((lane & 15) << 4))] = v;
    }
    __syncthreads();
    if ((w >> 1) == t) {
      const int rowbase = (w & 1) * 32;
#pragma unroll
      for (int pf = 0; pf < 2; ++pf) {
        int row = rowbase + pf * 16 + c;
#pragma unroll
        for (int kk = 0; kk < 8; ++kk) {
          int s = (kk << 2) | q;
          bfrag[pf][kk] =
              *(const short8*)&tileu[row * 256 + ((s * 8) ^ ((row & 15) << 4))];
        }
        float a = 0.f;
#pragma unroll
        for (int kk = 0; kk < 8; ++kk)
#pragma unroll
          for (int e = 0; e < 8; ++e) {
            unsigned u = ((unsigned)(unsigned short)bfrag[pf][kk][e]) << 16;
            float f = __builtin_bit_cast(float, u);
            a += f * f;
          }
        fn[pf] = a;
      }
#pragma unroll
      for (int pf = 0; pf < 2; ++pf) {
        fn[pf] += __shfl_xor(fn[pf], 16, 64);
        fn[pf] += __shfl_xor(fn[pf], 32, 64);
      }
    }
    __syncthreads();
  }

  // ---- stream 32 codebook chunks (16KB, double-buffered) ----
  float runD[2];
  int runI[2];
#pragma unroll
  for (int pf = 0; pf < 2; ++pf) { runD[pf] = 3.0e38f; runI[pf] = 0x7fffffff; }

#pragma unroll
  for (int r = 0; r < 4; ++r)
    async16(&dbuf[0][r * 256 + tid], cbimg + (r * 256 + tid));
  __syncthreads();

  int buf = 0;
#pragma unroll 1
  for (int chunk = 0; chunk < 32; ++chunk) {
    if (chunk < 31) {
#pragma unroll
      for (int r = 0; r < 4; ++r)
        async16(&dbuf[buf ^ 1][r * 256 + tid],
                cbimg + ((chunk + 1) * 1024 + r * 256 + tid));
    }
    float4v acc[2][2];
#pragma unroll
    for (int af = 0; af < 2; ++af) {
      float4v cn = *(const float4v*)&cnorm_s[chunk * 32 + af * 16 + q * 4];
#pragma unroll
      for (int pf = 0; pf < 2; ++pf) acc[af][pf] = cn;
    }
#pragma unroll
    for (int kk = 0; kk < 8; ++kk) {
      short8 a[2];
#pragma unroll
      for (int af = 0; af < 2; ++af)
        a[af] = dbuf[buf][(af * 16 + c) * 32 + (((kk << 2) | q) ^ (c << 1))];
#pragma unroll
      for (int af = 0; af < 2; ++af)
#pragma unroll
        for (int pf = 0; pf < 2; ++pf)
          acc[af][pf] = __builtin_amdgcn_mfma_f32_16x16x32_bf16(
              a[af], bfrag[pf][kk], acc[af][pf], 0, 0, 0);
    }
    // lane-local scan (ascending code index; strict < = first occurrence)
#pragma unroll
    for (int pf = 0; pf < 2; ++pf)
#pragma unroll
      for (int af = 0; af < 2; ++af) {
        int cb0 = chunk * 32 + af * 16 + q * 4;
#pragma unroll
        for (int r = 0; r < 4; ++r) {
          float dv = acc[af][pf][r];
          if (dv < runD[pf]) { runD[pf] = dv; runI[pf] = cb0 + r; }
        }
      }
    __syncthreads();
    buf ^= 1;
  }

  // ---- deferred butterfly merge over q-groups; idx to LDS; loss partial ----
#pragma unroll
  for (int pf = 0; pf < 2; ++pf) {
#pragma unroll
    for (int di = 16; di < 64; di <<= 1) {
      float od = __shfl_xor(runD[pf], di, 64);
      int oi = __shfl_xor(runI[pf], di, 64);
      if (od < runD[pf] || (od == runD[pf] && oi < runI[pf])) {
        runD[pf] = od; runI[pf] = oi;
      }
    }
  }
  if (q == 0) idx_s[w * 32 + c] = runI[0];
  if (q == 2) idx_s[w * 32 + 16 + c] = runI[1];
  float lv = q == 0 ? runD[0] + fn[0] : q == 2 ? runD[1] + fn[1] : 0.f;
#pragma unroll
  for (int off = 1; off < 64; off <<= 1) lv += __shfl_xor(lv, off, 64);
  if (lane == 0) part[blk * 4 + w] = lv;
  __syncthreads();

  // ---- gather-out: out[b,d,hw] = cb[idx[hw]][d] (L2-resident cb rows) ----
  const int hw4 = (tid & 31) * 4, dg = tid >> 5;
  int4v idx4 = *(const int4v*)&idx_s[hw4];
  const size_t outbase = ((size_t)b * D_) * HW_ + hwb + hw4;
#pragma unroll 4
  for (int it = 0; it < 32; ++it) {
    int d = it * 8 + dg;
    float4v v;
#pragma unroll
    for (int i = 0; i < 4; ++i) v[i] = cb[(size_t)idx4[i] * D_ + d];
    *(float4v*)&out[outbase + (size_t)d * HW_] = v;
  }
}

// ---- finalize: loss = 1.25 * mean (2048 partials) ----
__global__ __launch_bounds__(256) void vq_fin(const float* __restrict__ part,
                                              float* __restrict__ outs) {
  int t = threadIdx.x;
  float s = 0.f;
#pragma unroll
  for (int k = 0; k < 8; ++k) s += part[t + k * 256];
#pragma unroll
  for (int off = 1; off < 64; off <<= 1) s += __shfl_xor(s, off, 64);
  __shared__ float w4[4];
  if ((t & 63) == 0) w4[t >> 6] = s;
  __syncthreads();
  if (t == 0) *outs = (w4[0] + w4[1] + w4[2] + w4[3]) * (1.25f / 16777216.0f);
}

extern "C" void kernel_launch(void* const* d_in, const int* in_sizes, int n_in,
                              void* d_out, int out_size, void* d_ws, size_t ws_size,
                              hipStream_t stream) {
  const float* lat = (const float*)d_in[0];
  const float* cb = (const float*)d_in[1];
  float* out = (float*)d_out;
  char* ws = (char*)d_ws;
  unsigned short* cbimg = (unsigned short*)ws;   // 512 KB (bf16 -2c image)
  float* cnorm = (float*)(ws + 524288);          // 4 KB
  float* partial = (float*)(ws + 528384);        // 8 KB (2048 floats)

  vq_prep<<<1024, 256, 0, stream>>>(cb, cbimg, cnorm);
  vq_main<<<512, 256, 0, stream>>>(lat, (const short8*)cbimg, cnorm, cb, out,
                                   partial);
  vq_fin<<<1, 256, 0, stream>>>(partial, out + 16777216);
}